// Round 2
// baseline (1456.643 us; speedup 1.0000x reference)
//
#include <hip/hip_runtime.h>
#include <hip/hip_bf16.h>
#include <math.h>

// B=2, S=2048, H=4096, NH=32, NKV=8, HD=128, Q_SIZE=4096, KV_SIZE=1024, N_qkv=6144
// fp32 inputs/outputs; bf16 MFMA pipeline with fp32 accumulation.

typedef __attribute__((ext_vector_type(8))) __bf16 bf16x8;
typedef __attribute__((ext_vector_type(4))) float floatx4;

__device__ __forceinline__ floatx4 mfma16(bf16x8 a, bf16x8 b, floatx4 c) {
    return __builtin_amdgcn_mfma_f32_16x16x32_bf16(a, b, c, 0, 0, 0);
}

// async global->LDS, 16B per lane. dst must be wave-uniform base; HW writes
// lane i at dst + i*16B.  [m97: global_load_lds_dwordx4]
__device__ __forceinline__ void load_lds16(const __hip_bfloat16* g,
                                           __hip_bfloat16* lds_base_uniform) {
    __builtin_amdgcn_global_load_lds(
        (const __attribute__((address_space(1))) unsigned int*)g,
        (__attribute__((address_space(3))) unsigned int*)lds_base_uniform,
        16, 0, 0);
}

// ---------------------------------------------------------------------------
// fp32 -> bf16 elementwise convert. n % 1024 == 0.
// ---------------------------------------------------------------------------
__global__ __launch_bounds__(256)
void convert_kernel(const float* __restrict__ in, __hip_bfloat16* __restrict__ out,
                    int n) {
    int i = (blockIdx.x * 256 + threadIdx.x) * 4;
    if (i >= n) return;
    float4 v = *(const float4*)(in + i);
    union { __hip_bfloat16 h[4]; uint2 u; } pk;
    pk.h[0] = __float2bfloat16(v.x);
    pk.h[1] = __float2bfloat16(v.y);
    pk.h[2] = __float2bfloat16(v.z);
    pk.h[3] = __float2bfloat16(v.w);
    *(uint2*)(out + i) = pk.u;
}

// ---------------------------------------------------------------------------
// fp32 in[r][c] -> bf16 out[c][r] transpose (weights).
// ---------------------------------------------------------------------------
__global__ __launch_bounds__(256)
void transpose_f32_bf16_kernel(const float* __restrict__ in,
                               __hip_bfloat16* __restrict__ out, int R, int C) {
    __shared__ __hip_bfloat16 tile[64][65];
    const int r0 = blockIdx.y * 64, c0 = blockIdx.x * 64;
    const int t = threadIdx.x;
    #pragma unroll
    for (int i = 0; i < 16; ++i) {
        int idx = t + 256 * i;
        int rl = idx >> 6, cl = idx & 63;
        tile[rl][cl] = __float2bfloat16(in[(size_t)(r0 + rl) * C + (c0 + cl)]);
    }
    __syncthreads();
    #pragma unroll
    for (int i = 0; i < 16; ++i) {
        int idx = t + 256 * i;
        int cl = idx >> 6, rl = idx & 63;
        out[(size_t)(c0 + cl) * R + (r0 + rl)] = tile[rl][cl];
    }
}

// ---------------------------------------------------------------------------
// bf16 batched transpose: in[b][r][c] -> out[b][c][r].
// ---------------------------------------------------------------------------
__global__ __launch_bounds__(256)
void transpose_bf16_kernel(const __hip_bfloat16* __restrict__ in,
                           __hip_bfloat16* __restrict__ out, int R, int C) {
    __shared__ __hip_bfloat16 tile[64][65];
    const int bz = blockIdx.z;
    const __hip_bfloat16* inb  = in  + (size_t)bz * R * C;
    __hip_bfloat16*       outb = out + (size_t)bz * R * C;
    const int r0 = blockIdx.y * 64, c0 = blockIdx.x * 64;
    const int t = threadIdx.x;
    #pragma unroll
    for (int i = 0; i < 16; ++i) {
        int idx = t + 256 * i;
        int rl = idx >> 6, cl = idx & 63;
        tile[rl][cl] = inb[(size_t)(r0 + rl) * C + (c0 + cl)];
    }
    __syncthreads();
    #pragma unroll
    for (int i = 0; i < 16; ++i) {
        int idx = t + 256 * i;
        int cl = idx >> 6, rl = idx & 63;
        outb[(size_t)(c0 + cl) * R + (r0 + rl)] = tile[rl][cl];
    }
}

// ---------------------------------------------------------------------------
// bf16 GEMM: C[M,N] = A[M,K] * Bt[N,K]^T.  128x128 tile, BK=32, 4 waves.
// Staging via global_load_lds width=16 (m97).  LDS element offset = idx*8,
// so per-wave dest base = (wave*64 + 256*i)*8 — wave-uniform, lane*16B apart.
// MODE 0: fp32 store to Cp.  MODE 1: QKV scatter (bf16).
// ---------------------------------------------------------------------------
template <int MODE>
__global__ __launch_bounds__(256)
void gemm_bt_kernel(const __hip_bfloat16* __restrict__ A,
                    const __hip_bfloat16* __restrict__ Bt,
                    float* __restrict__ Cp,
                    __hip_bfloat16* __restrict__ Qr,
                    __hip_bfloat16* __restrict__ Kr,
                    __hip_bfloat16* __restrict__ Vv,
                    int M, int N, int K) {
    __shared__ __align__(16) __hip_bfloat16 As[128 * 32];
    __shared__ __align__(16) __hip_bfloat16 Bs[128 * 32];

    const int m0 = blockIdx.y * 128, n0 = blockIdx.x * 128;
    const int tid  = threadIdx.x;
    const int wave = tid >> 6, lane = tid & 63;
    const int quad = lane >> 4, l16 = lane & 15;
    const int wm = (wave >> 1) * 64, wn = (wave & 1) * 64;

    floatx4 acc[4][4] = {};

    for (int kt = 0; kt < K; kt += 32) {
        #pragma unroll
        for (int i = 0; i < 2; ++i) {
            int idx = tid + 256 * i;
            int row = idx >> 2;
            int kc  = (idx & 3) << 3;
            __hip_bfloat16* dstA = &As[(size_t)(wave * 64 + 256 * i) * 8];
            __hip_bfloat16* dstB = &Bs[(size_t)(wave * 64 + 256 * i) * 8];
            load_lds16(&A [(size_t)(m0 + row) * K + kt + kc], dstA);
            load_lds16(&Bt[(size_t)(n0 + row) * K + kt + kc], dstB);
        }
        __syncthreads();

        bf16x8 af[4], bfv[4];
        #pragma unroll
        for (int i = 0; i < 4; ++i)
            af[i]  = *(const bf16x8*)(&As[(wm + i * 16 + l16) * 32 + quad * 8]);
        #pragma unroll
        for (int j = 0; j < 4; ++j)
            bfv[j] = *(const bf16x8*)(&Bs[(wn + j * 16 + l16) * 32 + quad * 8]);
        #pragma unroll
        for (int i = 0; i < 4; ++i)
            #pragma unroll
            for (int j = 0; j < 4; ++j)
                acc[i][j] = mfma16(af[i], bfv[j], acc[i][j]);
        __syncthreads();
    }

    // C/D layout: col = lane&15, row = quad*4 + reg  [m89/m91]
    #pragma unroll
    for (int i = 0; i < 4; ++i) {
        #pragma unroll
        for (int j = 0; j < 4; ++j) {
            int col = n0 + wn + j * 16 + l16;
            #pragma unroll
            for (int r = 0; r < 4; ++r) {
                int row = m0 + wm + i * 16 + quad * 4 + r;
                if (MODE == 0) {
                    Cp[(size_t)row * N + col] = acc[i][j][r];
                } else {
                    __hip_bfloat16 v = __float2bfloat16(acc[i][j][r]);
                    int bb = row >> 11, s = row & 2047;
                    int d  = col & 127;
                    if (col < 4096) {
                        int h = col >> 7;
                        Qr[(((size_t)bb * 32 + h) * 2048 + s) * 128 + d] = v;
                    } else if (col < 5120) {
                        int kvh = (col - 4096) >> 7;
                        Kr[(((size_t)bb * 8 + kvh) * 2048 + s) * 128 + d] = v;
                    } else {
                        int kvh = (col - 5120) >> 7;
                        Vv[(((size_t)bb * 8 + kvh) * 2048 + s) * 128 + d] = v;
                    }
                }
            }
        }
    }
}

// ---------------------------------------------------------------------------
// In-place RoPE on x[row][128].  s = row & 2047, b = row >> bshift.
// qscale folds the attention 1/sqrt(HD) into Q for free.
// ---------------------------------------------------------------------------
__global__ __launch_bounds__(256)
void rope_kernel(__hip_bfloat16* __restrict__ x,
                 const int* __restrict__ positions, int nrows, int bshift,
                 float qscale) {
    int gid = blockIdx.x * 256 + threadIdx.x;
    if (gid >= nrows * 64) return;
    int row = gid >> 6, d = gid & 63;
    int s = row & 2047;
    int b = row >> bshift;
    float p = (float)positions[(b << 11) + s];
    float ang = p * expf(-0.14391156831212787f * (float)d);  // ln(1e4)/64
    float sn, cs;
    sincosf(ang, &sn, &cs);
    __hip_bfloat16* ptr = x + (size_t)row * 128;
    float x1 = __bfloat162float(ptr[d]);
    float x2 = __bfloat162float(ptr[d + 64]);
    ptr[d]      = __float2bfloat16((x1 * cs - x2 * sn) * qscale);
    ptr[d + 64] = __float2bfloat16((x2 * cs + x1 * sn) * qscale);
}

// ---------------------------------------------------------------------------
// Flash attention v2, causal, GQA.  256 threads = 4 waves; Q-tile = 128 rows
// (32/wave); K/V 64-key blocks staged in LDS via REGISTER prefetch (T14):
// tile t+1 loads issue after softmax (reusing sacc's dead regs), latency
// hides under the PV MFMA phase.  No __launch_bounds__ occupancy cap —
// round-1 showed a 170-VGPR cap spills ~1 GB of scratch per dispatch.
// LDS strides: Ks 132, Vs/Pl 68.  Q pre-scaled by 1/sqrt(128) in rope.
// blockIdx.x reversed: heavy causal blocks dispatch first.
// grid = (S/128, NH, B), block = 256.
// ---------------------------------------------------------------------------
__global__ __launch_bounds__(256)
void attn_kernel(const __hip_bfloat16* __restrict__ Qr,
                 const __hip_bfloat16* __restrict__ Kr,
                 const __hip_bfloat16* __restrict__ Vt,
                 __hip_bfloat16* __restrict__ Ao) {
    __shared__ __align__(16) __hip_bfloat16 Ks[64 * 132];   // 64 keys x 128d
    __shared__ __align__(16) __hip_bfloat16 Vs[128 * 68];   // 128 d x 64 keys
    __shared__ __align__(16) __hip_bfloat16 Pl[4][32 * 68]; // per-wave P 32x64

    const int tid  = threadIdx.x;
    const int wave = tid >> 6, lane = tid & 63;
    const int quad = lane >> 4, l16 = lane & 15;
    const int qb = (gridDim.x - 1) - blockIdx.x;      // heavy blocks first
    const int q0 = qb * 128;
    const int qr0 = q0 + wave * 32;                   // this wave's 32 rows
    const int h  = blockIdx.y;
    const int b  = blockIdx.z;
    const int kv = h >> 2;

    const __hip_bfloat16* Qb = Qr + ((size_t)b * 32 + h)  * 2048 * 128;
    const __hip_bfloat16* Kb = Kr + ((size_t)b * 8  + kv) * 2048 * 128;
    const __hip_bfloat16* Vb = Vt + ((size_t)b * 8  + kv) * 128 * 2048;

    // staging thread->element maps (64x128 K tile, 128x64 V tile, 16B each)
    const int krow = tid >> 4,            kcol = (tid & 15) << 3;   // +16 rows/p
    const int vrow = tid >> 3,            vcol = (tid & 7)  << 3;   // +32 rows/p

    // Q fragments resident: A-layout m=lane&15, k=quad*8+j
    bf16x8 qf[2][4];
    #pragma unroll
    for (int i = 0; i < 2; ++i)
        #pragma unroll
        for (int kc = 0; kc < 4; ++kc)
            qf[i][kc] = *(const bf16x8*)(
                &Qb[(size_t)(qr0 + i * 16 + l16) * 128 + kc * 32 + quad * 8]);

    float m_i[2][4], l_i[2][4];
    #pragma unroll
    for (int i = 0; i < 2; ++i)
        #pragma unroll
        for (int r = 0; r < 4; ++r) { m_i[i][r] = -1e30f; l_i[i][r] = 0.0f; }
    floatx4 o[2][8] = {};

    const int kmax = q0 + 127;                 // block-level causal max row

    // ---- prologue: stage tile 0 into registers ----
    uint4 kreg[4], vreg[4];
    #pragma unroll
    for (int p = 0; p < 4; ++p) {
        kreg[p] = *(const uint4*)(&Kb[(size_t)(krow + 16 * p) * 128 + kcol]);
        vreg[p] = *(const uint4*)(&Vb[(size_t)(vrow + 32 * p) * 2048 + vcol]);
    }

    for (int ks = 0; ks <= kmax; ks += 64) {
        // ---- write staged regs -> LDS ----
        #pragma unroll
        for (int p = 0; p < 4; ++p) {
            *(uint4*)(&Ks[(krow + 16 * p) * 132 + kcol]) = kreg[p];
            *(uint4*)(&Vs[(vrow + 32 * p) * 68  + vcol]) = vreg[p];
        }
        __syncthreads();

        const bool live  = (ks <= qr0 + 31);   // wave-uniform causal guard
        const bool fullt = (ks + 63 <= qr0);   // no masking needed this tile

        if (live) {
            // ---- S = Q K^T  (64 keys) ----
            floatx4 sacc[2][4] = {};
            __builtin_amdgcn_s_setprio(1);
            #pragma unroll
            for (int kc = 0; kc < 4; ++kc) {
                bf16x8 kf[4];
                #pragma unroll
                for (int j = 0; j < 4; ++j)
                    kf[j] = *(const bf16x8*)(
                        &Ks[(j * 16 + l16) * 132 + kc * 32 + quad * 8]);
                #pragma unroll
                for (int i = 0; i < 2; ++i)
                    #pragma unroll
                    for (int j = 0; j < 4; ++j)
                        sacc[i][j] = mfma16(qf[i][kc], kf[j], sacc[i][j]);
            }
            __builtin_amdgcn_s_setprio(0);

            // ---- online softmax; O-rescale inline; P -> per-wave LDS ----
            #pragma unroll
            for (int i = 0; i < 2; ++i) {
                #pragma unroll
                for (int r = 0; r < 4; ++r) {
                    int row = qr0 + i * 16 + quad * 4 + r;
                    float s[4];
                    #pragma unroll
                    for (int j = 0; j < 4; ++j) s[j] = sacc[i][j][r];
                    if (!fullt) {
                        #pragma unroll
                        for (int j = 0; j < 4; ++j)
                            if (ks + j * 16 + l16 > row) s[j] = -1e30f;
                    }
                    float mx = fmaxf(fmaxf(s[0], s[1]), fmaxf(s[2], s[3]));
                    #pragma unroll
                    for (int off = 1; off < 16; off <<= 1)
                        mx = fmaxf(mx, __shfl_xor(mx, off, 64));
                    float mnew = fmaxf(m_i[i][r], mx);
                    float a  = __expf(m_i[i][r] - mnew);
                    float rs = 0.0f;
                    #pragma unroll
                    for (int j = 0; j < 4; ++j) {
                        float p = __expf(s[j] - mnew);
                        rs += p;
                        Pl[wave][(i * 16 + quad * 4 + r) * 68 + j * 16 + l16] =
                            __float2bfloat16(p);
                    }
                    #pragma unroll
                    for (int off = 1; off < 16; off <<= 1)
                        rs += __shfl_xor(rs, off, 64);
                    l_i[i][r] = l_i[i][r] * a + rs;
                    m_i[i][r] = mnew;
                    #pragma unroll
                    for (int dn = 0; dn < 8; ++dn)
                        o[i][dn][r] *= a;
                }
            }
        }

        // ---- prefetch next K/V tile into regs (hides under PV below) ----
        if (ks + 64 <= kmax) {
            #pragma unroll
            for (int p = 0; p < 4; ++p) {
                kreg[p] = *(const uint4*)(
                    &Kb[(size_t)(ks + 64 + krow + 16 * p) * 128 + kcol]);
                vreg[p] = *(const uint4*)(
                    &Vb[(size_t)(vrow + 32 * p) * 2048 + ks + 64 + vcol]);
            }
        }

        if (live) {
            // ---- P fragments (A-layout) ----
            bf16x8 pf[2][2];
            #pragma unroll
            for (int i = 0; i < 2; ++i)
                #pragma unroll
                for (int k2 = 0; k2 < 2; ++k2)
                    pf[i][k2] = *(const bf16x8*)(
                        &Pl[wave][(i * 16 + l16) * 68 + k2 * 32 + quad * 8]);

            // ---- O += P V ----
            __builtin_amdgcn_s_setprio(1);
            #pragma unroll
            for (int dn = 0; dn < 8; ++dn) {
                #pragma unroll
                for (int k2 = 0; k2 < 2; ++k2) {
                    bf16x8 vf = *(const bf16x8*)(
                        &Vs[(dn * 16 + l16) * 68 + k2 * 32 + quad * 8]);
                    #pragma unroll
                    for (int i = 0; i < 2; ++i)
                        o[i][dn] = mfma16(pf[i][k2], vf, o[i][dn]);
                }
            }
            __builtin_amdgcn_s_setprio(0);
        }
        __syncthreads();
    }

    // ---- write Ao[b][s][h*128+d] ----
    #pragma unroll
    for (int i = 0; i < 2; ++i) {
        #pragma unroll
        for (int r = 0; r < 4; ++r) {
            float inv = 1.0f / l_i[i][r];
            int row = qr0 + i * 16 + quad * 4 + r;
            size_t base = ((size_t)b * 2048 + row) * 4096 + (size_t)h * 128;
            #pragma unroll
            for (int dn = 0; dn < 8; ++dn)
                Ao[base + dn * 16 + l16] = __float2bfloat16(o[i][dn][r] * inv);
        }
    }
}

// ---------------------------------------------------------------------------
extern "C" void kernel_launch(void* const* d_in, const int* in_sizes, int n_in,
                              void* d_out, int out_size, void* d_ws, size_t ws_size,
                              hipStream_t stream) {
    const int*   positions = (const int*)d_in[0];
    const float* hidden    = (const float*)d_in[1];
    const float* wqkv      = (const float*)d_in[2];
    const float* wo        = (const float*)d_in[3];
    float* out = (float*)d_out;

    __hip_bfloat16* WqkvT = (__hip_bfloat16*)d_ws;        // 25165824
    __hip_bfloat16* WoT   = WqkvT + 25165824;             // 16777216
    __hip_bfloat16* Hb    = WoT   + 16777216;             // 16777216
    __hip_bfloat16* Qr    = Hb    + 16777216;             // 16777216
    __hip_bfloat16* Kr    = Qr    + 16777216;             // 4194304
    __hip_bfloat16* Vv    = Kr    + 4194304;              // 4194304
    __hip_bfloat16* Ao    = WqkvT;                        // alias (dead after GEMM1)
    __hip_bfloat16* Vt    = Hb;                           // alias (dead after GEMM1)
    // total 160 MiB

    convert_kernel<<<16777216 / 1024, 256, 0, stream>>>(hidden, Hb, 16777216);
    transpose_f32_bf16_kernel<<<dim3(6144 / 64, 4096 / 64), 256, 0, stream>>>(
        wqkv, WqkvT, 4096, 6144);
    transpose_f32_bf16_kernel<<<dim3(4096 / 64, 4096 / 64), 256, 0, stream>>>(
        wo, WoT, 4096, 4096);

    gemm_bt_kernel<1><<<dim3(6144 / 128, 4096 / 128), 256, 0, stream>>>(
        Hb, WqkvT, nullptr, Qr, Kr, Vv, 4096, 6144, 4096);

    rope_kernel<<<(131072 * 64) / 256, 256, 0, stream>>>(
        Qr, positions, 131072, 16, 0.08838834764831845f);
    rope_kernel<<<(32768  * 64) / 256, 256, 0, stream>>>(
        Kr, positions, 32768, 14, 1.0f);

    transpose_bf16_kernel<<<dim3(128 / 64, 2048 / 64, 16), 256, 0, stream>>>(
        Vv, Vt, 2048, 128);

    attn_kernel<<<dim3(2048 / 128, 32, 2), 256, 0, stream>>>(Qr, Kr, Vt, Ao);

    gemm_bt_kernel<0><<<dim3(4096 / 128, 4096 / 128), 256, 0, stream>>>(
        Ao, WoT, out, nullptr, nullptr, nullptr, 4096, 4096, 4096);
}

// Round 4
// 1081.689 us; speedup vs baseline: 1.3466x; 1.3466x over previous
//
#include <hip/hip_runtime.h>
#include <hip/hip_bf16.h>
#include <math.h>

// B=2, S=2048, H=4096, NH=32, NKV=8, HD=128, Q_SIZE=4096, KV_SIZE=1024, N_qkv=6144
// fp32 inputs/outputs; bf16 MFMA pipeline with fp32 accumulation.

typedef __attribute__((ext_vector_type(8))) __bf16 bf16x8;
typedef __attribute__((ext_vector_type(4))) float floatx4;

__device__ __forceinline__ floatx4 mfma16(bf16x8 a, bf16x8 b, floatx4 c) {
    return __builtin_amdgcn_mfma_f32_16x16x32_bf16(a, b, c, 0, 0, 0);
}

// async global->LDS, 16B per lane. dst must be wave-uniform base; HW writes
// lane i at dst + i*16B.  [m97: global_load_lds_dwordx4]
__device__ __forceinline__ void load_lds16(const __hip_bfloat16* g,
                                           __hip_bfloat16* lds_base_uniform) {
    __builtin_amdgcn_global_load_lds(
        (const __attribute__((address_space(1))) unsigned int*)g,
        (__attribute__((address_space(3))) unsigned int*)lds_base_uniform,
        16, 0, 0);
}

// ---------------------------------------------------------------------------
// fp32 -> bf16 elementwise convert. n % 1024 == 0.
// ---------------------------------------------------------------------------
__global__ __launch_bounds__(256)
void convert_kernel(const float* __restrict__ in, __hip_bfloat16* __restrict__ out,
                    int n) {
    int i = (blockIdx.x * 256 + threadIdx.x) * 4;
    if (i >= n) return;
    float4 v = *(const float4*)(in + i);
    union { __hip_bfloat16 h[4]; uint2 u; } pk;
    pk.h[0] = __float2bfloat16(v.x);
    pk.h[1] = __float2bfloat16(v.y);
    pk.h[2] = __float2bfloat16(v.z);
    pk.h[3] = __float2bfloat16(v.w);
    *(uint2*)(out + i) = pk.u;
}

// ---------------------------------------------------------------------------
// fp32 in[r][c] -> bf16 out[c][r] transpose (weights).
// ---------------------------------------------------------------------------
__global__ __launch_bounds__(256)
void transpose_f32_bf16_kernel(const float* __restrict__ in,
                               __hip_bfloat16* __restrict__ out, int R, int C) {
    __shared__ __hip_bfloat16 tile[64][65];
    const int r0 = blockIdx.y * 64, c0 = blockIdx.x * 64;
    const int t = threadIdx.x;
    #pragma unroll
    for (int i = 0; i < 16; ++i) {
        int idx = t + 256 * i;
        int rl = idx >> 6, cl = idx & 63;
        tile[rl][cl] = __float2bfloat16(in[(size_t)(r0 + rl) * C + (c0 + cl)]);
    }
    __syncthreads();
    #pragma unroll
    for (int i = 0; i < 16; ++i) {
        int idx = t + 256 * i;
        int cl = idx >> 6, rl = idx & 63;
        out[(size_t)(c0 + cl) * R + (r0 + rl)] = tile[rl][cl];
    }
}

// ---------------------------------------------------------------------------
// bf16 batched transpose: in[b][r][c] -> out[b][c][r].
// ---------------------------------------------------------------------------
__global__ __launch_bounds__(256)
void transpose_bf16_kernel(const __hip_bfloat16* __restrict__ in,
                           __hip_bfloat16* __restrict__ out, int R, int C) {
    __shared__ __hip_bfloat16 tile[64][65];
    const int bz = blockIdx.z;
    const __hip_bfloat16* inb  = in  + (size_t)bz * R * C;
    __hip_bfloat16*       outb = out + (size_t)bz * R * C;
    const int r0 = blockIdx.y * 64, c0 = blockIdx.x * 64;
    const int t = threadIdx.x;
    #pragma unroll
    for (int i = 0; i < 16; ++i) {
        int idx = t + 256 * i;
        int rl = idx >> 6, cl = idx & 63;
        tile[rl][cl] = inb[(size_t)(r0 + rl) * C + (c0 + cl)];
    }
    __syncthreads();
    #pragma unroll
    for (int i = 0; i < 16; ++i) {
        int idx = t + 256 * i;
        int cl = idx >> 6, rl = idx & 63;
        outb[(size_t)(c0 + cl) * R + (r0 + rl)] = tile[rl][cl];
    }
}

// ---------------------------------------------------------------------------
// bf16 GEMM: C[M,N] = A[M,K] * Bt[N,K]^T.  128x128 tile, BK=32, 4 waves.
// Staging via global_load_lds width=16 (m97).  LDS element offset = idx*8,
// so per-wave dest base = (wave*64 + 256*i)*8 — wave-uniform, lane*16B apart.
// MODE 0: fp32 store to Cp.  MODE 1: QKV scatter (bf16).
// ---------------------------------------------------------------------------
template <int MODE>
__global__ __launch_bounds__(256)
void gemm_bt_kernel(const __hip_bfloat16* __restrict__ A,
                    const __hip_bfloat16* __restrict__ Bt,
                    float* __restrict__ Cp,
                    __hip_bfloat16* __restrict__ Qr,
                    __hip_bfloat16* __restrict__ Kr,
                    __hip_bfloat16* __restrict__ Vv,
                    int M, int N, int K) {
    __shared__ __align__(16) __hip_bfloat16 As[128 * 32];
    __shared__ __align__(16) __hip_bfloat16 Bs[128 * 32];

    const int m0 = blockIdx.y * 128, n0 = blockIdx.x * 128;
    const int tid  = threadIdx.x;
    const int wave = tid >> 6, lane = tid & 63;
    const int quad = lane >> 4, l16 = lane & 15;
    const int wm = (wave >> 1) * 64, wn = (wave & 1) * 64;

    floatx4 acc[4][4] = {};

    for (int kt = 0; kt < K; kt += 32) {
        #pragma unroll
        for (int i = 0; i < 2; ++i) {
            int idx = tid + 256 * i;
            int row = idx >> 2;
            int kc  = (idx & 3) << 3;
            __hip_bfloat16* dstA = &As[(size_t)(wave * 64 + 256 * i) * 8];
            __hip_bfloat16* dstB = &Bs[(size_t)(wave * 64 + 256 * i) * 8];
            load_lds16(&A [(size_t)(m0 + row) * K + kt + kc], dstA);
            load_lds16(&Bt[(size_t)(n0 + row) * K + kt + kc], dstB);
        }
        __syncthreads();

        bf16x8 af[4], bfv[4];
        #pragma unroll
        for (int i = 0; i < 4; ++i)
            af[i]  = *(const bf16x8*)(&As[(wm + i * 16 + l16) * 32 + quad * 8]);
        #pragma unroll
        for (int j = 0; j < 4; ++j)
            bfv[j] = *(const bf16x8*)(&Bs[(wn + j * 16 + l16) * 32 + quad * 8]);
        #pragma unroll
        for (int i = 0; i < 4; ++i)
            #pragma unroll
            for (int j = 0; j < 4; ++j)
                acc[i][j] = mfma16(af[i], bfv[j], acc[i][j]);
        __syncthreads();
    }

    // C/D layout: col = lane&15, row = quad*4 + reg  [m89/m91]
    #pragma unroll
    for (int i = 0; i < 4; ++i) {
        #pragma unroll
        for (int j = 0; j < 4; ++j) {
            int col = n0 + wn + j * 16 + l16;
            #pragma unroll
            for (int r = 0; r < 4; ++r) {
                int row = m0 + wm + i * 16 + quad * 4 + r;
                if (MODE == 0) {
                    Cp[(size_t)row * N + col] = acc[i][j][r];
                } else {
                    __hip_bfloat16 v = __float2bfloat16(acc[i][j][r]);
                    int bb = row >> 11, s = row & 2047;
                    int d  = col & 127;
                    if (col < 4096) {
                        int h = col >> 7;
                        Qr[(((size_t)bb * 32 + h) * 2048 + s) * 128 + d] = v;
                    } else if (col < 5120) {
                        int kvh = (col - 4096) >> 7;
                        Kr[(((size_t)bb * 8 + kvh) * 2048 + s) * 128 + d] = v;
                    } else {
                        int kvh = (col - 5120) >> 7;
                        Vv[(((size_t)bb * 8 + kvh) * 2048 + s) * 128 + d] = v;
                    }
                }
            }
        }
    }
}

// ---------------------------------------------------------------------------
// In-place RoPE on x[row][128].  s = row & 2047, b = row >> bshift.
// qscale folds the attention 1/sqrt(HD) into Q for free.
// ---------------------------------------------------------------------------
__global__ __launch_bounds__(256)
void rope_kernel(__hip_bfloat16* __restrict__ x,
                 const int* __restrict__ positions, int nrows, int bshift,
                 float qscale) {
    int gid = blockIdx.x * 256 + threadIdx.x;
    if (gid >= nrows * 64) return;
    int row = gid >> 6, d = gid & 63;
    int s = row & 2047;
    int b = row >> bshift;
    float p = (float)positions[(b << 11) + s];
    float ang = p * expf(-0.14391156831212787f * (float)d);  // ln(1e4)/64
    float sn, cs;
    sincosf(ang, &sn, &cs);
    __hip_bfloat16* ptr = x + (size_t)row * 128;
    float x1 = __bfloat162float(ptr[d]);
    float x2 = __bfloat162float(ptr[d + 64]);
    ptr[d]      = __float2bfloat16((x1 * cs - x2 * sn) * qscale);
    ptr[d + 64] = __float2bfloat16((x2 * cs + x1 * sn) * qscale);
}

// ---------------------------------------------------------------------------
// Flash attention v2, causal, GQA.  Round-0 proven resource envelope:
// 256 threads = 4 waves, Q-tile 128 (32 rows/wave), KVBLK=32, synchronous
// LDS staging, strides Ks 136 / Vs 36 / Pl 40 — VGPR<=128 (4 waves/SIMD),
// LDS 28160 B (5 blocks/CU) -> all 1024 blocks co-resident (4/CU).
// Deltas vs round 0 (resource-neutral):
//   - l-sum via ones-MFMA: lsum[i] = mfma(pf[i], ones, lsum[i]) replaces the
//     16-lane sum butterfly (-32 shfl_xor/iter); O and l now use identical
//     bf16 P weights (exact weighted average).
//   - full-tile mask skip (ks+31 <= qr0).
//   - Q pre-scaled by 1/sqrt(128) in rope.
//   - s_setprio(1) around MFMA clusters (m191).
// blockIdx.x reversed: heavy causal blocks dispatch first.
// grid = (S/128, NH, B), block = 256.
// ---------------------------------------------------------------------------
__global__ __launch_bounds__(256)
void attn_kernel(const __hip_bfloat16* __restrict__ Qr,
                 const __hip_bfloat16* __restrict__ Kr,
                 const __hip_bfloat16* __restrict__ Vt,
                 __hip_bfloat16* __restrict__ Ao) {
    __shared__ __align__(16) __hip_bfloat16 Ks[32 * 136];
    __shared__ __align__(16) __hip_bfloat16 Vs[128 * 36];
    __shared__ __align__(16) __hip_bfloat16 Pl[4][32 * 40];

    const int tid  = threadIdx.x;
    const int wave = tid >> 6, lane = tid & 63;
    const int quad = lane >> 4, l16 = lane & 15;
    const int qb = (gridDim.x - 1) - blockIdx.x;      // heavy blocks first
    const int q0 = qb * 128;
    const int qr0 = q0 + wave * 32;                   // this wave's 32 rows
    const int h  = blockIdx.y;
    const int b  = blockIdx.z;
    const int kv = h >> 2;

    const __hip_bfloat16* Qb = Qr + ((size_t)b * 32 + h)  * 2048 * 128;
    const __hip_bfloat16* Kb = Kr + ((size_t)b * 8  + kv) * 2048 * 128;
    const __hip_bfloat16* Vb = Vt + ((size_t)b * 8  + kv) * 128 * 2048;

    // Q fragments resident: A-layout m=lane&15, k=quad*8+j
    bf16x8 qf[2][4];
    #pragma unroll
    for (int i = 0; i < 2; ++i)
        #pragma unroll
        for (int kc = 0; kc < 4; ++kc)
            qf[i][kc] = *(const bf16x8*)(
                &Qb[(size_t)(qr0 + i * 16 + l16) * 128 + kc * 32 + quad * 8]);

    float m_i[2][4];
    #pragma unroll
    for (int i = 0; i < 2; ++i)
        #pragma unroll
        for (int r = 0; r < 4; ++r) m_i[i][r] = -1e30f;
    floatx4 o[2][8] = {};
    floatx4 lsum[2] = {};

    // all-ones B operand for the l row-sum MFMA
    bf16x8 ones;
    #pragma unroll
    for (int e = 0; e < 8; ++e) ones[e] = (__bf16)1.0f;

    const int kmax = q0 + 127;                 // block-level causal max row

    for (int ks = 0; ks <= kmax; ks += 32) {
        // ---- cooperative staging: K 32x128 -> Ks[32][136] ----
        #pragma unroll
        for (int p = 0; p < 2; ++p) {
            int idx = tid + 256 * p;
            int krow = idx >> 4, kcol = (idx & 15) << 3;
            *(uint4*)(&Ks[krow * 136 + kcol]) =
                *(const uint4*)(&Kb[(size_t)(ks + krow) * 128 + kcol]);
        }
        // ---- V 128x32 (Vt rows = d) -> Vs[128][36] ----
        #pragma unroll
        for (int p = 0; p < 2; ++p) {
            int idx = tid + 256 * p;
            int d = idx >> 2, koff = (idx & 3) << 3;
            *(uint4*)(&Vs[d * 36 + koff]) =
                *(const uint4*)(&Vb[(size_t)d * 2048 + ks + koff]);
        }
        __syncthreads();

        if (ks <= qr0 + 31) {   // wave-uniform causal guard
            const bool fullt = (ks + 31 <= qr0);   // no masking needed

            // ---- S = Q K^T ----
            floatx4 sacc[2][2] = {};
            __builtin_amdgcn_s_setprio(1);
            #pragma unroll
            for (int j = 0; j < 2; ++j) {
                #pragma unroll
                for (int kc = 0; kc < 4; ++kc) {
                    bf16x8 kf = *(const bf16x8*)(
                        &Ks[(j * 16 + l16) * 136 + kc * 32 + quad * 8]);
                    #pragma unroll
                    for (int i = 0; i < 2; ++i)
                        sacc[i][j] = mfma16(qf[i][kc], kf, sacc[i][j]);
                }
            }
            __builtin_amdgcn_s_setprio(0);

            // ---- online softmax (max butterfly only; sum via MFMA) ----
            #pragma unroll
            for (int i = 0; i < 2; ++i) {
                #pragma unroll
                for (int r = 0; r < 4; ++r) {
                    int row = qr0 + i * 16 + quad * 4 + r;
                    float s0 = sacc[i][0][r];
                    float s1 = sacc[i][1][r];
                    if (!fullt) {
                        if (ks + l16 > row)      s0 = -1e30f;
                        if (ks + 16 + l16 > row) s1 = -1e30f;
                    }
                    float mx = fmaxf(s0, s1);
                    #pragma unroll
                    for (int off = 1; off < 16; off <<= 1)
                        mx = fmaxf(mx, __shfl_xor(mx, off, 64));
                    float mnew = fmaxf(m_i[i][r], mx);
                    float a  = __expf(m_i[i][r] - mnew);
                    float p0 = __expf(s0 - mnew);
                    float p1 = __expf(s1 - mnew);
                    Pl[wave][(i * 16 + quad * 4 + r) * 40 + l16]      =
                        __float2bfloat16(p0);
                    Pl[wave][(i * 16 + quad * 4 + r) * 40 + 16 + l16] =
                        __float2bfloat16(p1);
                    m_i[i][r] = mnew;
                    lsum[i][r] *= a;
                    #pragma unroll
                    for (int dn = 0; dn < 8; ++dn)
                        o[i][dn][r] *= a;
                }
            }

            // ---- P fragments (A-layout) ----
            bf16x8 pf[2];
            #pragma unroll
            for (int i = 0; i < 2; ++i)
                pf[i] = *(const bf16x8*)(&Pl[wave][(i * 16 + l16) * 40 + quad * 8]);

            // ---- O += P V ; l += P * ones ----
            __builtin_amdgcn_s_setprio(1);
            #pragma unroll
            for (int i = 0; i < 2; ++i)
                lsum[i] = mfma16(pf[i], ones, lsum[i]);
            #pragma unroll
            for (int dn = 0; dn < 8; ++dn) {
                bf16x8 vf = *(const bf16x8*)(
                    &Vs[(dn * 16 + l16) * 36 + quad * 8]);
                #pragma unroll
                for (int i = 0; i < 2; ++i)
                    o[i][dn] = mfma16(pf[i], vf, o[i][dn]);
            }
            __builtin_amdgcn_s_setprio(0);
        }
        __syncthreads();
    }

    // ---- write Ao[b][s][h*128+d] ----
    #pragma unroll
    for (int i = 0; i < 2; ++i) {
        #pragma unroll
        for (int r = 0; r < 4; ++r) {
            float inv = 1.0f / lsum[i][r];
            int row = qr0 + i * 16 + quad * 4 + r;
            size_t base = ((size_t)b * 2048 + row) * 4096 + (size_t)h * 128;
            #pragma unroll
            for (int dn = 0; dn < 8; ++dn)
                Ao[base + dn * 16 + l16] = __float2bfloat16(o[i][dn][r] * inv);
        }
    }
}

// ---------------------------------------------------------------------------
extern "C" void kernel_launch(void* const* d_in, const int* in_sizes, int n_in,
                              void* d_out, int out_size, void* d_ws, size_t ws_size,
                              hipStream_t stream) {
    const int*   positions = (const int*)d_in[0];
    const float* hidden    = (const float*)d_in[1];
    const float* wqkv      = (const float*)d_in[2];
    const float* wo        = (const float*)d_in[3];
    float* out = (float*)d_out;

    __hip_bfloat16* WqkvT = (__hip_bfloat16*)d_ws;        // 25165824
    __hip_bfloat16* WoT   = WqkvT + 25165824;             // 16777216
    __hip_bfloat16* Hb    = WoT   + 16777216;             // 16777216
    __hip_bfloat16* Qr    = Hb    + 16777216;             // 16777216
    __hip_bfloat16* Kr    = Qr    + 16777216;             // 4194304
    __hip_bfloat16* Vv    = Kr    + 4194304;              // 4194304
    __hip_bfloat16* Ao    = WqkvT;                        // alias (dead after GEMM1)
    __hip_bfloat16* Vt    = Hb;                           // alias (dead after GEMM1)
    // total 160 MiB

    convert_kernel<<<16777216 / 1024, 256, 0, stream>>>(hidden, Hb, 16777216);
    transpose_f32_bf16_kernel<<<dim3(6144 / 64, 4096 / 64), 256, 0, stream>>>(
        wqkv, WqkvT, 4096, 6144);
    transpose_f32_bf16_kernel<<<dim3(4096 / 64, 4096 / 64), 256, 0, stream>>>(
        wo, WoT, 4096, 4096);

    gemm_bt_kernel<1><<<dim3(6144 / 128, 4096 / 128), 256, 0, stream>>>(
        Hb, WqkvT, nullptr, Qr, Kr, Vv, 4096, 6144, 4096);

    rope_kernel<<<(131072 * 64) / 256, 256, 0, stream>>>(
        Qr, positions, 131072, 16, 0.08838834764831845f);
    rope_kernel<<<(32768  * 64) / 256, 256, 0, stream>>>(
        Kr, positions, 32768, 14, 1.0f);

    transpose_bf16_kernel<<<dim3(128 / 64, 2048 / 64, 16), 256, 0, stream>>>(
        Vv, Vt, 2048, 128);

    attn_kernel<<<dim3(2048 / 128, 32, 2), 256, 0, stream>>>(Qr, Kr, Vt, Ao);

    gemm_bt_kernel<0><<<dim3(4096 / 128, 4096 / 128), 256, 0, stream>>>(
        Ao, WoT, out, nullptr, nullptr, nullptr, 4096, 4096, 4096);
}

// Round 5
// 1011.001 us; speedup vs baseline: 1.4408x; 1.0699x over previous
//
#include <hip/hip_runtime.h>
#include <hip/hip_bf16.h>
#include <math.h>

// B=2, S=2048, H=4096, NH=32, NKV=8, HD=128, Q_SIZE=4096, KV_SIZE=1024, N_qkv=6144
// fp32 inputs/outputs; bf16 MFMA pipeline with fp32 accumulation.

typedef __attribute__((ext_vector_type(8))) __bf16 bf16x8;
typedef __attribute__((ext_vector_type(4))) float floatx4;

__device__ __forceinline__ floatx4 mfma16(bf16x8 a, bf16x8 b, floatx4 c) {
    return __builtin_amdgcn_mfma_f32_16x16x32_bf16(a, b, c, 0, 0, 0);
}

// async global->LDS, 16B per lane. dst must be wave-uniform base; HW writes
// lane i at dst + i*16B.  [m97: global_load_lds_dwordx4]
__device__ __forceinline__ void load_lds16(const __hip_bfloat16* g,
                                           __hip_bfloat16* lds_base_uniform) {
    __builtin_amdgcn_global_load_lds(
        (const __attribute__((address_space(1))) unsigned int*)g,
        (__attribute__((address_space(3))) unsigned int*)lds_base_uniform,
        16, 0, 0);
}

// ---------------------------------------------------------------------------
// fp32 -> bf16 elementwise convert. n % 1024 == 0.
// ---------------------------------------------------------------------------
__global__ __launch_bounds__(256)
void convert_kernel(const float* __restrict__ in, __hip_bfloat16* __restrict__ out,
                    int n) {
    int i = (blockIdx.x * 256 + threadIdx.x) * 4;
    if (i >= n) return;
    float4 v = *(const float4*)(in + i);
    union { __hip_bfloat16 h[4]; uint2 u; } pk;
    pk.h[0] = __float2bfloat16(v.x);
    pk.h[1] = __float2bfloat16(v.y);
    pk.h[2] = __float2bfloat16(v.z);
    pk.h[3] = __float2bfloat16(v.w);
    *(uint2*)(out + i) = pk.u;
}

// ---------------------------------------------------------------------------
// fp32 in[r][c] -> bf16 out[c][r] transpose (weights).
// ---------------------------------------------------------------------------
__global__ __launch_bounds__(256)
void transpose_f32_bf16_kernel(const float* __restrict__ in,
                               __hip_bfloat16* __restrict__ out, int R, int C) {
    __shared__ __hip_bfloat16 tile[64][65];
    const int r0 = blockIdx.y * 64, c0 = blockIdx.x * 64;
    const int t = threadIdx.x;
    #pragma unroll
    for (int i = 0; i < 16; ++i) {
        int idx = t + 256 * i;
        int rl = idx >> 6, cl = idx & 63;
        tile[rl][cl] = __float2bfloat16(in[(size_t)(r0 + rl) * C + (c0 + cl)]);
    }
    __syncthreads();
    #pragma unroll
    for (int i = 0; i < 16; ++i) {
        int idx = t + 256 * i;
        int cl = idx >> 6, rl = idx & 63;
        out[(size_t)(c0 + cl) * R + (r0 + rl)] = tile[rl][cl];
    }
}

// ---------------------------------------------------------------------------
// bf16 batched transpose: in[b][r][c] -> out[b][c][r].
// ---------------------------------------------------------------------------
__global__ __launch_bounds__(256)
void transpose_bf16_kernel(const __hip_bfloat16* __restrict__ in,
                           __hip_bfloat16* __restrict__ out, int R, int C) {
    __shared__ __hip_bfloat16 tile[64][65];
    const int bz = blockIdx.z;
    const __hip_bfloat16* inb  = in  + (size_t)bz * R * C;
    __hip_bfloat16*       outb = out + (size_t)bz * R * C;
    const int r0 = blockIdx.y * 64, c0 = blockIdx.x * 64;
    const int t = threadIdx.x;
    #pragma unroll
    for (int i = 0; i < 16; ++i) {
        int idx = t + 256 * i;
        int rl = idx >> 6, cl = idx & 63;
        tile[rl][cl] = inb[(size_t)(r0 + rl) * C + (c0 + cl)];
    }
    __syncthreads();
    #pragma unroll
    for (int i = 0; i < 16; ++i) {
        int idx = t + 256 * i;
        int cl = idx >> 6, rl = idx & 63;
        outb[(size_t)(c0 + cl) * R + (r0 + rl)] = tile[rl][cl];
    }
}

// ---------------------------------------------------------------------------
// bf16 GEMM: C[M,N] = A[M,K] * Bt[N,K]^T.  128x128 tile, BK=32, 4 waves.
// Staging via global_load_lds width=16 (m97).  LDS element offset = idx*8,
// so per-wave dest base = (wave*64 + 256*i)*8 — wave-uniform, lane*16B apart.
// MODE 0: fp32 store to Cp.  MODE 1: QKV scatter (bf16).
// ---------------------------------------------------------------------------
template <int MODE>
__global__ __launch_bounds__(256)
void gemm_bt_kernel(const __hip_bfloat16* __restrict__ A,
                    const __hip_bfloat16* __restrict__ Bt,
                    float* __restrict__ Cp,
                    __hip_bfloat16* __restrict__ Qr,
                    __hip_bfloat16* __restrict__ Kr,
                    __hip_bfloat16* __restrict__ Vv,
                    int M, int N, int K) {
    __shared__ __align__(16) __hip_bfloat16 As[128 * 32];
    __shared__ __align__(16) __hip_bfloat16 Bs[128 * 32];

    const int m0 = blockIdx.y * 128, n0 = blockIdx.x * 128;
    const int tid  = threadIdx.x;
    const int wave = tid >> 6, lane = tid & 63;
    const int quad = lane >> 4, l16 = lane & 15;
    const int wm = (wave >> 1) * 64, wn = (wave & 1) * 64;

    floatx4 acc[4][4] = {};

    for (int kt = 0; kt < K; kt += 32) {
        #pragma unroll
        for (int i = 0; i < 2; ++i) {
            int idx = tid + 256 * i;
            int row = idx >> 2;
            int kc  = (idx & 3) << 3;
            __hip_bfloat16* dstA = &As[(size_t)(wave * 64 + 256 * i) * 8];
            __hip_bfloat16* dstB = &Bs[(size_t)(wave * 64 + 256 * i) * 8];
            load_lds16(&A [(size_t)(m0 + row) * K + kt + kc], dstA);
            load_lds16(&Bt[(size_t)(n0 + row) * K + kt + kc], dstB);
        }
        __syncthreads();

        bf16x8 af[4], bfv[4];
        #pragma unroll
        for (int i = 0; i < 4; ++i)
            af[i]  = *(const bf16x8*)(&As[(wm + i * 16 + l16) * 32 + quad * 8]);
        #pragma unroll
        for (int j = 0; j < 4; ++j)
            bfv[j] = *(const bf16x8*)(&Bs[(wn + j * 16 + l16) * 32 + quad * 8]);
        #pragma unroll
        for (int i = 0; i < 4; ++i)
            #pragma unroll
            for (int j = 0; j < 4; ++j)
                acc[i][j] = mfma16(af[i], bfv[j], acc[i][j]);
        __syncthreads();
    }

    // C/D layout: col = lane&15, row = quad*4 + reg  [m89/m91]
    #pragma unroll
    for (int i = 0; i < 4; ++i) {
        #pragma unroll
        for (int j = 0; j < 4; ++j) {
            int col = n0 + wn + j * 16 + l16;
            #pragma unroll
            for (int r = 0; r < 4; ++r) {
                int row = m0 + wm + i * 16 + quad * 4 + r;
                if (MODE == 0) {
                    Cp[(size_t)row * N + col] = acc[i][j][r];
                } else {
                    __hip_bfloat16 v = __float2bfloat16(acc[i][j][r]);
                    int bb = row >> 11, s = row & 2047;
                    int d  = col & 127;
                    if (col < 4096) {
                        int h = col >> 7;
                        Qr[(((size_t)bb * 32 + h) * 2048 + s) * 128 + d] = v;
                    } else if (col < 5120) {
                        int kvh = (col - 4096) >> 7;
                        Kr[(((size_t)bb * 8 + kvh) * 2048 + s) * 128 + d] = v;
                    } else {
                        int kvh = (col - 5120) >> 7;
                        Vv[(((size_t)bb * 8 + kvh) * 2048 + s) * 128 + d] = v;
                    }
                }
            }
        }
    }
}

// ---------------------------------------------------------------------------
// In-place RoPE on x[row][128].  s = row & 2047, b = row >> bshift.
// qscale folds the attention 1/sqrt(HD) into Q for free.
// ---------------------------------------------------------------------------
__global__ __launch_bounds__(256)
void rope_kernel(__hip_bfloat16* __restrict__ x,
                 const int* __restrict__ positions, int nrows, int bshift,
                 float qscale) {
    int gid = blockIdx.x * 256 + threadIdx.x;
    if (gid >= nrows * 64) return;
    int row = gid >> 6, d = gid & 63;
    int s = row & 2047;
    int b = row >> bshift;
    float p = (float)positions[(b << 11) + s];
    float ang = p * expf(-0.14391156831212787f * (float)d);  // ln(1e4)/64
    float sn, cs;
    sincosf(ang, &sn, &cs);
    __hip_bfloat16* ptr = x + (size_t)row * 128;
    float x1 = __bfloat162float(ptr[d]);
    float x2 = __bfloat162float(ptr[d + 64]);
    ptr[d]      = __float2bfloat16((x1 * cs - x2 * sn) * qscale);
    ptr[d + 64] = __float2bfloat16((x2 * cs + x1 * sn) * qscale);
}

// ---------------------------------------------------------------------------
// Flash attention v2, causal, GQA.  Round-5 structure:
//   - DOUBLE-BUFFERED K/V in LDS via global_load_lds (async): tile t+1's
//     loads issue before tile t's compute; the compiler's vmcnt(0) drain at
//     the single end-of-iteration barrier lands after ~2-3K cycles of
//     compute, hiding the staging latency.  ONE barrier per iteration.
//   - Unpadded LDS + XOR swizzle (rule 21: linear dest, inverse-swizzled
//     global source, swizzled read).  K: c16 ^= row&7 (kf reads 2-way =
//     free).  V, Pl: c16 ^= row&3 (4-way).
//   - LDS budget exact: Ks 2x8K + Vs 2x8K + Pl 8K = 40960 B = 160KiB/4
//     -> 4 blocks/CU (VGPR 128 = 4 waves/SIMD still binding).
//   - Balanced causal grid: blocks {l, l+256, l+512, l+768} share a CU
//     (round-robin); qb = (h&16) ? x : 15-x makes each CU's 4 blocks sum
//     to a constant 136 iterations (kills the straggler tail).
//   - Carried from round 4: ones-MFMA l-sum, full-tile mask skip,
//     Q pre-scaled by 1/sqrt(128), s_setprio around MFMA clusters.
// grid = (S/128, NH, B), block = 256 (4 waves, 32 q-rows each).
// ---------------------------------------------------------------------------
__device__ __forceinline__ void stage_tiles(const __hip_bfloat16* __restrict__ Kb,
                                            const __hip_bfloat16* __restrict__ Vb,
                                            int ks,
                                            __hip_bfloat16* KsBuf,
                                            __hip_bfloat16* VsBuf,
                                            int tid, int wave) {
    #pragma unroll
    for (int p = 0; p < 2; ++p) {
        int idx  = tid + 256 * p;
        int krow = idx >> 4, kc16 = idx & 15;            // K tile 32 x 128
        load_lds16(&Kb[(size_t)(ks + krow) * 128 + ((kc16 ^ (krow & 7)) << 3)],
                   &KsBuf[(wave * 64 + 256 * p) * 8]);
        int vrow = idx >> 2, vc16 = idx & 3;             // V tile 128 x 32
        load_lds16(&Vb[(size_t)vrow * 2048 + ks + ((vc16 ^ (vrow & 3)) << 3)],
                   &VsBuf[(wave * 64 + 256 * p) * 8]);
    }
}

__global__ __launch_bounds__(256)
void attn_kernel(const __hip_bfloat16* __restrict__ Qr,
                 const __hip_bfloat16* __restrict__ Kr,
                 const __hip_bfloat16* __restrict__ Vt,
                 __hip_bfloat16* __restrict__ Ao) {
    __shared__ __align__(16) __hip_bfloat16 Ks[2][32 * 128];  // swizzled c16^row&7
    __shared__ __align__(16) __hip_bfloat16 Vs[2][128 * 32];  // swizzled c16^row&3
    __shared__ __align__(16) __hip_bfloat16 Pl[4][32 * 32];   // swizzled c16^row&3

    const int tid  = threadIdx.x;
    const int wave = tid >> 6, lane = tid & 63;
    const int quad = lane >> 4, l16 = lane & 15;
    // balanced causal pairing: co-resident blocks sum to constant work
    const int qb = (blockIdx.y & 16) ? blockIdx.x : (15 - blockIdx.x);
    const int q0 = qb * 128;
    const int qr0 = q0 + wave * 32;                   // this wave's 32 rows
    const int h  = blockIdx.y;
    const int b  = blockIdx.z;
    const int kv = h >> 2;

    const __hip_bfloat16* Qb = Qr + ((size_t)b * 32 + h)  * 2048 * 128;
    const __hip_bfloat16* Kb = Kr + ((size_t)b * 8  + kv) * 2048 * 128;
    const __hip_bfloat16* Vb = Vt + ((size_t)b * 8  + kv) * 128 * 2048;

    // Q fragments resident: A-layout m=lane&15, k=quad*8+j
    bf16x8 qf[2][4];
    #pragma unroll
    for (int i = 0; i < 2; ++i)
        #pragma unroll
        for (int kc = 0; kc < 4; ++kc)
            qf[i][kc] = *(const bf16x8*)(
                &Qb[(size_t)(qr0 + i * 16 + l16) * 128 + kc * 32 + quad * 8]);

    float m_i[2][4];
    #pragma unroll
    for (int i = 0; i < 2; ++i)
        #pragma unroll
        for (int r = 0; r < 4; ++r) m_i[i][r] = -1e30f;
    floatx4 o[2][8] = {};
    floatx4 lsum[2] = {};

    // all-ones B operand for the l row-sum MFMA
    bf16x8 ones;
    #pragma unroll
    for (int e = 0; e < 8; ++e) ones[e] = (__bf16)1.0f;

    const int ntiles = (q0 >> 5) + 4;          // (q0+128)/32

    // ---- prologue: stage tile 0 into buffer 0 ----
    stage_tiles(Kb, Vb, 0, Ks[0], Vs[0], tid, wave);
    __syncthreads();

    int cur = 0;
    for (int t = 0; t < ntiles; ++t) {
        const int ks = t << 5;

        // ---- issue next tile's async loads into the other buffer ----
        if (t + 1 < ntiles)
            stage_tiles(Kb, Vb, ks + 32, Ks[cur ^ 1], Vs[cur ^ 1], tid, wave);

        if (ks <= qr0 + 31) {   // wave-uniform causal guard
            const __hip_bfloat16* Kc = Ks[cur];
            const __hip_bfloat16* Vc = Vs[cur];
            const bool fullt = (ks + 31 <= qr0);   // no masking needed

            // ---- S = Q K^T ----
            floatx4 sacc[2][2] = {};
            __builtin_amdgcn_s_setprio(1);
            #pragma unroll
            for (int j = 0; j < 2; ++j) {
                #pragma unroll
                for (int kc = 0; kc < 4; ++kc) {
                    bf16x8 kf = *(const bf16x8*)(
                        &Kc[(j * 16 + l16) * 128 +
                            (((kc * 4 + quad) ^ (l16 & 7)) << 3)]);
                    #pragma unroll
                    for (int i = 0; i < 2; ++i)
                        sacc[i][j] = mfma16(qf[i][kc], kf, sacc[i][j]);
                }
            }
            __builtin_amdgcn_s_setprio(0);

            // ---- online softmax (max butterfly only; sum via MFMA) ----
            #pragma unroll
            for (int i = 0; i < 2; ++i) {
                #pragma unroll
                for (int r = 0; r < 4; ++r) {
                    int row = qr0 + i * 16 + quad * 4 + r;
                    float s0 = sacc[i][0][r];
                    float s1 = sacc[i][1][r];
                    if (!fullt) {
                        if (ks + l16 > row)      s0 = -1e30f;
                        if (ks + 16 + l16 > row) s1 = -1e30f;
                    }
                    float mx = fmaxf(s0, s1);
                    #pragma unroll
                    for (int off = 1; off < 16; off <<= 1)
                        mx = fmaxf(mx, __shfl_xor(mx, off, 64));
                    float mnew = fmaxf(m_i[i][r], mx);
                    float a  = __expf(m_i[i][r] - mnew);
                    float p0 = __expf(s0 - mnew);
                    float p1 = __expf(s1 - mnew);
                    int prow = i * 16 + quad * 4 + r;
                    Pl[wave][prow * 32 + (((l16 >> 3) ^ r) << 3) + (l16 & 7)] =
                        __float2bfloat16(p0);
                    Pl[wave][prow * 32 + (((2 + (l16 >> 3)) ^ r) << 3) + (l16 & 7)] =
                        __float2bfloat16(p1);
                    m_i[i][r] = mnew;
                    lsum[i][r] *= a;
                    #pragma unroll
                    for (int dn = 0; dn < 8; ++dn)
                        o[i][dn][r] *= a;
                }
            }

            // ---- P fragments (A-layout, swizzled read) ----
            bf16x8 pf[2];
            #pragma unroll
            for (int i = 0; i < 2; ++i)
                pf[i] = *(const bf16x8*)(
                    &Pl[wave][(i * 16 + l16) * 32 + ((quad ^ (l16 & 3)) << 3)]);

            // ---- O += P V ; l += P * ones ----
            __builtin_amdgcn_s_setprio(1);
            #pragma unroll
            for (int i = 0; i < 2; ++i)
                lsum[i] = mfma16(pf[i], ones, lsum[i]);
            #pragma unroll
            for (int dn = 0; dn < 8; ++dn) {
                bf16x8 vf = *(const bf16x8*)(
                    &Vc[(dn * 16 + l16) * 32 + ((quad ^ (l16 & 3)) << 3)]);
                #pragma unroll
                for (int i = 0; i < 2; ++i)
                    o[i][dn] = mfma16(pf[i], vf, o[i][dn]);
            }
            __builtin_amdgcn_s_setprio(0);
        }
        __syncthreads();   // drains vmcnt(0): next tile's loads have landed
        cur ^= 1;
    }

    // ---- write Ao[b][s][h*128+d] ----
    #pragma unroll
    for (int i = 0; i < 2; ++i) {
        #pragma unroll
        for (int r = 0; r < 4; ++r) {
            float inv = 1.0f / lsum[i][r];
            int row = qr0 + i * 16 + quad * 4 + r;
            size_t base = ((size_t)b * 2048 + row) * 4096 + (size_t)h * 128;
            #pragma unroll
            for (int dn = 0; dn < 8; ++dn)
                Ao[base + dn * 16 + l16] = __float2bfloat16(o[i][dn][r] * inv);
        }
    }
}

// ---------------------------------------------------------------------------
extern "C" void kernel_launch(void* const* d_in, const int* in_sizes, int n_in,
                              void* d_out, int out_size, void* d_ws, size_t ws_size,
                              hipStream_t stream) {
    const int*   positions = (const int*)d_in[0];
    const float* hidden    = (const float*)d_in[1];
    const float* wqkv      = (const float*)d_in[2];
    const float* wo        = (const float*)d_in[3];
    float* out = (float*)d_out;

    __hip_bfloat16* WqkvT = (__hip_bfloat16*)d_ws;        // 25165824
    __hip_bfloat16* WoT   = WqkvT + 25165824;             // 16777216
    __hip_bfloat16* Hb    = WoT   + 16777216;             // 16777216
    __hip_bfloat16* Qr    = Hb    + 16777216;             // 16777216
    __hip_bfloat16* Kr    = Qr    + 16777216;             // 4194304
    __hip_bfloat16* Vv    = Kr    + 4194304;              // 4194304
    __hip_bfloat16* Ao    = WqkvT;                        // alias (dead after GEMM1)
    __hip_bfloat16* Vt    = Hb;                           // alias (dead after GEMM1)
    // total 160 MiB

    convert_kernel<<<16777216 / 1024, 256, 0, stream>>>(hidden, Hb, 16777216);
    transpose_f32_bf16_kernel<<<dim3(6144 / 64, 4096 / 64), 256, 0, stream>>>(
        wqkv, WqkvT, 4096, 6144);
    transpose_f32_bf16_kernel<<<dim3(4096 / 64, 4096 / 64), 256, 0, stream>>>(
        wo, WoT, 4096, 4096);

    gemm_bt_kernel<1><<<dim3(6144 / 128, 4096 / 128), 256, 0, stream>>>(
        Hb, WqkvT, nullptr, Qr, Kr, Vv, 4096, 6144, 4096);

    rope_kernel<<<(131072 * 64) / 256, 256, 0, stream>>>(
        Qr, positions, 131072, 16, 0.08838834764831845f);
    rope_kernel<<<(32768  * 64) / 256, 256, 0, stream>>>(
        Kr, positions, 32768, 14, 1.0f);

    transpose_bf16_kernel<<<dim3(128 / 64, 2048 / 64, 16), 256, 0, stream>>>(
        Vv, Vt, 2048, 128);

    attn_kernel<<<dim3(2048 / 128, 32, 2), 256, 0, stream>>>(Qr, Kr, Vt, Ao);

    gemm_bt_kernel<0><<<dim3(4096 / 128, 4096 / 128), 256, 0, stream>>>(
        Ao, WoT, out, nullptr, nullptr, nullptr, 4096, 4096, 4096);
}

// Round 6
// 1005.331 us; speedup vs baseline: 1.4489x; 1.0056x over previous
//
#include <hip/hip_runtime.h>
#include <hip/hip_bf16.h>
#include <math.h>

// B=2, S=2048, H=4096, NH=32, NKV=8, HD=128, Q_SIZE=4096, KV_SIZE=1024, N_qkv=6144
// fp32 inputs/outputs; bf16 MFMA pipeline with fp32 accumulation.

typedef __attribute__((ext_vector_type(8))) __bf16 bf16x8;
typedef __attribute__((ext_vector_type(4))) float floatx4;

__device__ __forceinline__ floatx4 mfma16(bf16x8 a, bf16x8 b, floatx4 c) {
    return __builtin_amdgcn_mfma_f32_16x16x32_bf16(a, b, c, 0, 0, 0);
}

// async global->LDS, 16B per lane. dst must be wave-uniform base; HW writes
// lane i at dst + i*16B.  [m97: global_load_lds_dwordx4]
__device__ __forceinline__ void load_lds16(const __hip_bfloat16* g,
                                           __hip_bfloat16* lds_base_uniform) {
    __builtin_amdgcn_global_load_lds(
        (const __attribute__((address_space(1))) unsigned int*)g,
        (__attribute__((address_space(3))) unsigned int*)lds_base_uniform,
        16, 0, 0);
}

// counted-vmcnt tile sync (T4): allow N newest global_load_lds to stay in
// flight across the barrier; sched_barrier fences stop hipcc reordering.
__device__ __forceinline__ void sync_vm6() {
    __builtin_amdgcn_sched_barrier(0);
    asm volatile("s_waitcnt vmcnt(6)" ::: "memory");
    __builtin_amdgcn_s_barrier();
    __builtin_amdgcn_sched_barrier(0);
}
__device__ __forceinline__ void sync_vm0() {
    __builtin_amdgcn_sched_barrier(0);
    asm volatile("s_waitcnt vmcnt(0)" ::: "memory");
    __builtin_amdgcn_s_barrier();
    __builtin_amdgcn_sched_barrier(0);
}

// ---------------------------------------------------------------------------
// fp32 -> bf16 elementwise convert. n % 1024 == 0.
// ---------------------------------------------------------------------------
__global__ __launch_bounds__(256)
void convert_kernel(const float* __restrict__ in, __hip_bfloat16* __restrict__ out,
                    int n) {
    int i = (blockIdx.x * 256 + threadIdx.x) * 4;
    if (i >= n) return;
    float4 v = *(const float4*)(in + i);
    union { __hip_bfloat16 h[4]; uint2 u; } pk;
    pk.h[0] = __float2bfloat16(v.x);
    pk.h[1] = __float2bfloat16(v.y);
    pk.h[2] = __float2bfloat16(v.z);
    pk.h[3] = __float2bfloat16(v.w);
    *(uint2*)(out + i) = pk.u;
}

// ---------------------------------------------------------------------------
// fp32 in[r][c] -> bf16 out[c][r] transpose (weights).
// ---------------------------------------------------------------------------
__global__ __launch_bounds__(256)
void transpose_f32_bf16_kernel(const float* __restrict__ in,
                               __hip_bfloat16* __restrict__ out, int R, int C) {
    __shared__ __hip_bfloat16 tile[64][65];
    const int r0 = blockIdx.y * 64, c0 = blockIdx.x * 64;
    const int t = threadIdx.x;
    #pragma unroll
    for (int i = 0; i < 16; ++i) {
        int idx = t + 256 * i;
        int rl = idx >> 6, cl = idx & 63;
        tile[rl][cl] = __float2bfloat16(in[(size_t)(r0 + rl) * C + (c0 + cl)]);
    }
    __syncthreads();
    #pragma unroll
    for (int i = 0; i < 16; ++i) {
        int idx = t + 256 * i;
        int cl = idx >> 6, rl = idx & 63;
        out[(size_t)(c0 + cl) * R + (r0 + rl)] = tile[rl][cl];
    }
}

// ---------------------------------------------------------------------------
// bf16 batched transpose: in[b][r][c] -> out[b][c][r].
// ---------------------------------------------------------------------------
__global__ __launch_bounds__(256)
void transpose_bf16_kernel(const __hip_bfloat16* __restrict__ in,
                           __hip_bfloat16* __restrict__ out, int R, int C) {
    __shared__ __hip_bfloat16 tile[64][65];
    const int bz = blockIdx.z;
    const __hip_bfloat16* inb  = in  + (size_t)bz * R * C;
    __hip_bfloat16*       outb = out + (size_t)bz * R * C;
    const int r0 = blockIdx.y * 64, c0 = blockIdx.x * 64;
    const int t = threadIdx.x;
    #pragma unroll
    for (int i = 0; i < 16; ++i) {
        int idx = t + 256 * i;
        int rl = idx >> 6, cl = idx & 63;
        tile[rl][cl] = inb[(size_t)(r0 + rl) * C + (c0 + cl)];
    }
    __syncthreads();
    #pragma unroll
    for (int i = 0; i < 16; ++i) {
        int idx = t + 256 * i;
        int cl = idx >> 6, rl = idx & 63;
        outb[(size_t)(c0 + cl) * R + (r0 + rl)] = tile[rl][cl];
    }
}

// ---------------------------------------------------------------------------
// bf16 GEMM: C[M,N] = A[M,K] * Bt[N,K]^T.  Round-6 deep-pipelined version:
//   BM=128, BN=256, BK=64; 512 threads = 8 waves (2M x 4N), wave out 64x64
//   (acc[4][4] = 64 VGPR).  LDS: 3-buffer rotation (As 16KB + Bs 32KB each,
//   144 KB total, 1 block/CU), staged via global_load_lds (6 loads/thread
//   per K-tile, linear dest + inverse-XOR-swizzled global source; ds_read
//   applies the same XOR -> conflict-reduced b128 reads).
//   Counted vmcnt (T4): per tile wait vmcnt(6) -- tile t must have landed,
//   tile t+1's 6 loads stay in flight across the barrier; stage(t+2) is
//   issued right after the barrier so its loads get ~2 tiles of MFMA cover.
//   ONE barrier per K-tile.  s_setprio(1) around the MFMA cluster (T5).
// MODE 0: fp32 store to Cp.  MODE 1: QKV scatter (bf16).
// grid = (N/256, M/128); both our GEMMs give exact multiples of 256 blocks
// (768 and 512) -> no dispatch-round tail at 1 block/CU.
// ---------------------------------------------------------------------------
template <int MODE>
__global__ __launch_bounds__(512)
void gemm_bt_kernel(const __hip_bfloat16* __restrict__ A,
                    const __hip_bfloat16* __restrict__ Bt,
                    float* __restrict__ Cp,
                    __hip_bfloat16* __restrict__ Qr,
                    __hip_bfloat16* __restrict__ Kr,
                    __hip_bfloat16* __restrict__ Vv,
                    int M, int N, int K) {
    __shared__ __align__(16) __hip_bfloat16 As[3][128 * 64];
    __shared__ __align__(16) __hip_bfloat16 Bs[3][256 * 64];

    const int m0 = blockIdx.y * 128, n0 = blockIdx.x * 256;
    const int tid  = threadIdx.x;
    const int wave = tid >> 6, lane = tid & 63;
    const int quad = lane >> 4, l16 = lane & 15;
    const int wm = (wave >> 2) * 64, wn = (wave & 3) * 64;
    const int srow = tid >> 3, sg = tid & 7;   // staging: 8 threads/row

    floatx4 acc[4][4] = {};

    // stage one K-tile (A 128x64 in 2 rounds, B 256x64 in 4 rounds) into buf c.
    // global source granule = g ^ (row&7); LDS dest linear  [rule 21]
    auto stage = [&](int kt, int c) {
        #pragma unroll
        for (int r = 0; r < 2; ++r) {
            int row = srow + 64 * r;
            load_lds16(&A[(size_t)(m0 + row) * K + kt + ((sg ^ (row & 7)) << 3)],
                       &As[c][(wave * 64 + 512 * r) * 8]);
        }
        #pragma unroll
        for (int r = 0; r < 4; ++r) {
            int row = srow + 64 * r;
            load_lds16(&Bt[(size_t)(n0 + row) * K + kt + ((sg ^ (row & 7)) << 3)],
                       &Bs[c][(wave * 64 + 512 * r) * 8]);
        }
    };

    auto compute = [&](int c) {
        #pragma unroll
        for (int kk = 0; kk < 2; ++kk) {
            bf16x8 af[4], bf[4];
            #pragma unroll
            for (int i = 0; i < 4; ++i) {
                int row = wm + i * 16 + l16;
                af[i] = *(const bf16x8*)(
                    &As[c][row * 64 + (((kk * 4 + quad) ^ (row & 7)) << 3)]);
            }
            #pragma unroll
            for (int j = 0; j < 4; ++j) {
                int row = wn + j * 16 + l16;
                bf[j] = *(const bf16x8*)(
                    &Bs[c][row * 64 + (((kk * 4 + quad) ^ (row & 7)) << 3)]);
            }
            __builtin_amdgcn_s_setprio(1);
            #pragma unroll
            for (int i = 0; i < 4; ++i)
                #pragma unroll
                for (int j = 0; j < 4; ++j)
                    acc[i][j] = mfma16(af[i], bf[j], acc[i][j]);
            __builtin_amdgcn_s_setprio(0);
        }
    };

    const int NT = K >> 6;
    stage(0, 0);
    stage(64, 1);
    int cc = 0;
    #pragma unroll 1
    for (int t = 0; t < NT; ++t) {
        if (t < NT - 1) sync_vm6(); else sync_vm0();
        int cs = cc + 2; if (cs >= 3) cs -= 3;
        if (t + 2 < NT) stage((t + 2) << 6, cs);
        compute(cc);
        if (++cc == 3) cc = 0;
    }

    // C/D layout: col = lane&15, row = quad*4 + reg  [m89/m91]
    #pragma unroll
    for (int i = 0; i < 4; ++i) {
        #pragma unroll
        for (int j = 0; j < 4; ++j) {
            int col = n0 + wn + j * 16 + l16;
            #pragma unroll
            for (int r = 0; r < 4; ++r) {
                int row = m0 + wm + i * 16 + quad * 4 + r;
                if (MODE == 0) {
                    Cp[(size_t)row * N + col] = acc[i][j][r];
                } else {
                    __hip_bfloat16 v = __float2bfloat16(acc[i][j][r]);
                    int bb = row >> 11, s = row & 2047;
                    int d  = col & 127;
                    if (col < 4096) {
                        int h = col >> 7;
                        Qr[(((size_t)bb * 32 + h) * 2048 + s) * 128 + d] = v;
                    } else if (col < 5120) {
                        int kvh = (col - 4096) >> 7;
                        Kr[(((size_t)bb * 8 + kvh) * 2048 + s) * 128 + d] = v;
                    } else {
                        int kvh = (col - 5120) >> 7;
                        Vv[(((size_t)bb * 8 + kvh) * 2048 + s) * 128 + d] = v;
                    }
                }
            }
        }
    }
}

// ---------------------------------------------------------------------------
// In-place RoPE on x[row][128].  s = row & 2047, b = row >> bshift.
// qscale folds the attention 1/sqrt(HD) into Q for free.
// ---------------------------------------------------------------------------
__global__ __launch_bounds__(256)
void rope_kernel(__hip_bfloat16* __restrict__ x,
                 const int* __restrict__ positions, int nrows, int bshift,
                 float qscale) {
    int gid = blockIdx.x * 256 + threadIdx.x;
    if (gid >= nrows * 64) return;
    int row = gid >> 6, d = gid & 63;
    int s = row & 2047;
    int b = row >> bshift;
    float p = (float)positions[(b << 11) + s];
    float ang = p * expf(-0.14391156831212787f * (float)d);  // ln(1e4)/64
    float sn, cs;
    sincosf(ang, &sn, &cs);
    __hip_bfloat16* ptr = x + (size_t)row * 128;
    float x1 = __bfloat162float(ptr[d]);
    float x2 = __bfloat162float(ptr[d + 64]);
    ptr[d]      = __float2bfloat16((x1 * cs - x2 * sn) * qscale);
    ptr[d + 64] = __float2bfloat16((x2 * cs + x1 * sn) * qscale);
}

// ---------------------------------------------------------------------------
// Flash attention v2, causal, GQA.  (unchanged from round 5)
// Double-buffered K/V via global_load_lds, XOR-swizzled LDS, one barrier per
// 32-key tile, ones-MFMA l-sum, full-tile mask skip, balanced causal grid.
// grid = (S/128, NH, B), block = 256 (4 waves, 32 q-rows each).
// ---------------------------------------------------------------------------
__device__ __forceinline__ void stage_tiles(const __hip_bfloat16* __restrict__ Kb,
                                            const __hip_bfloat16* __restrict__ Vb,
                                            int ks,
                                            __hip_bfloat16* KsBuf,
                                            __hip_bfloat16* VsBuf,
                                            int tid, int wave) {
    #pragma unroll
    for (int p = 0; p < 2; ++p) {
        int idx  = tid + 256 * p;
        int krow = idx >> 4, kc16 = idx & 15;            // K tile 32 x 128
        load_lds16(&Kb[(size_t)(ks + krow) * 128 + ((kc16 ^ (krow & 7)) << 3)],
                   &KsBuf[(wave * 64 + 256 * p) * 8]);
        int vrow = idx >> 2, vc16 = idx & 3;             // V tile 128 x 32
        load_lds16(&Vb[(size_t)vrow * 2048 + ks + ((vc16 ^ (vrow & 3)) << 3)],
                   &VsBuf[(wave * 64 + 256 * p) * 8]);
    }
}

__global__ __launch_bounds__(256)
void attn_kernel(const __hip_bfloat16* __restrict__ Qr,
                 const __hip_bfloat16* __restrict__ Kr,
                 const __hip_bfloat16* __restrict__ Vt,
                 __hip_bfloat16* __restrict__ Ao) {
    __shared__ __align__(16) __hip_bfloat16 Ks[2][32 * 128];  // swizzled c16^row&7
    __shared__ __align__(16) __hip_bfloat16 Vs[2][128 * 32];  // swizzled c16^row&3
    __shared__ __align__(16) __hip_bfloat16 Pl[4][32 * 32];   // swizzled c16^row&3

    const int tid  = threadIdx.x;
    const int wave = tid >> 6, lane = tid & 63;
    const int quad = lane >> 4, l16 = lane & 15;
    // balanced causal pairing: co-resident blocks sum to constant work
    const int qb = (blockIdx.y & 16) ? blockIdx.x : (15 - blockIdx.x);
    const int q0 = qb * 128;
    const int qr0 = q0 + wave * 32;                   // this wave's 32 rows
    const int h  = blockIdx.y;
    const int b  = blockIdx.z;
    const int kv = h >> 2;

    const __hip_bfloat16* Qb = Qr + ((size_t)b * 32 + h)  * 2048 * 128;
    const __hip_bfloat16* Kb = Kr + ((size_t)b * 8  + kv) * 2048 * 128;
    const __hip_bfloat16* Vb = Vt + ((size_t)b * 8  + kv) * 128 * 2048;

    // Q fragments resident: A-layout m=lane&15, k=quad*8+j
    bf16x8 qf[2][4];
    #pragma unroll
    for (int i = 0; i < 2; ++i)
        #pragma unroll
        for (int kc = 0; kc < 4; ++kc)
            qf[i][kc] = *(const bf16x8*)(
                &Qb[(size_t)(qr0 + i * 16 + l16) * 128 + kc * 32 + quad * 8]);

    float m_i[2][4];
    #pragma unroll
    for (int i = 0; i < 2; ++i)
        #pragma unroll
        for (int r = 0; r < 4; ++r) m_i[i][r] = -1e30f;
    floatx4 o[2][8] = {};
    floatx4 lsum[2] = {};

    // all-ones B operand for the l row-sum MFMA
    bf16x8 ones;
    #pragma unroll
    for (int e = 0; e < 8; ++e) ones[e] = (__bf16)1.0f;

    const int ntiles = (q0 >> 5) + 4;          // (q0+128)/32

    // ---- prologue: stage tile 0 into buffer 0 ----
    stage_tiles(Kb, Vb, 0, Ks[0], Vs[0], tid, wave);
    __syncthreads();

    int cur = 0;
    for (int t = 0; t < ntiles; ++t) {
        const int ks = t << 5;

        // ---- issue next tile's async loads into the other buffer ----
        if (t + 1 < ntiles)
            stage_tiles(Kb, Vb, ks + 32, Ks[cur ^ 1], Vs[cur ^ 1], tid, wave);

        if (ks <= qr0 + 31) {   // wave-uniform causal guard
            const __hip_bfloat16* Kc = Ks[cur];
            const __hip_bfloat16* Vc = Vs[cur];
            const bool fullt = (ks + 31 <= qr0);   // no masking needed

            // ---- S = Q K^T ----
            floatx4 sacc[2][2] = {};
            __builtin_amdgcn_s_setprio(1);
            #pragma unroll
            for (int j = 0; j < 2; ++j) {
                #pragma unroll
                for (int kc = 0; kc < 4; ++kc) {
                    bf16x8 kf = *(const bf16x8*)(
                        &Kc[(j * 16 + l16) * 128 +
                            (((kc * 4 + quad) ^ (l16 & 7)) << 3)]);
                    #pragma unroll
                    for (int i = 0; i < 2; ++i)
                        sacc[i][j] = mfma16(qf[i][kc], kf, sacc[i][j]);
                }
            }
            __builtin_amdgcn_s_setprio(0);

            // ---- online softmax (max butterfly only; sum via MFMA) ----
            #pragma unroll
            for (int i = 0; i < 2; ++i) {
                #pragma unroll
                for (int r = 0; r < 4; ++r) {
                    int row = qr0 + i * 16 + quad * 4 + r;
                    float s0 = sacc[i][0][r];
                    float s1 = sacc[i][1][r];
                    if (!fullt) {
                        if (ks + l16 > row)      s0 = -1e30f;
                        if (ks + 16 + l16 > row) s1 = -1e30f;
                    }
                    float mx = fmaxf(s0, s1);
                    #pragma unroll
                    for (int off = 1; off < 16; off <<= 1)
                        mx = fmaxf(mx, __shfl_xor(mx, off, 64));
                    float mnew = fmaxf(m_i[i][r], mx);
                    float a  = __expf(m_i[i][r] - mnew);
                    float p0 = __expf(s0 - mnew);
                    float p1 = __expf(s1 - mnew);
                    int prow = i * 16 + quad * 4 + r;
                    Pl[wave][prow * 32 + (((l16 >> 3) ^ r) << 3) + (l16 & 7)] =
                        __float2bfloat16(p0);
                    Pl[wave][prow * 32 + (((2 + (l16 >> 3)) ^ r) << 3) + (l16 & 7)] =
                        __float2bfloat16(p1);
                    m_i[i][r] = mnew;
                    lsum[i][r] *= a;
                    #pragma unroll
                    for (int dn = 0; dn < 8; ++dn)
                        o[i][dn][r] *= a;
                }
            }

            // ---- P fragments (A-layout, swizzled read) ----
            bf16x8 pf[2];
            #pragma unroll
            for (int i = 0; i < 2; ++i)
                pf[i] = *(const bf16x8*)(
                    &Pl[wave][(i * 16 + l16) * 32 + ((quad ^ (l16 & 3)) << 3)]);

            // ---- O += P V ; l += P * ones ----
            __builtin_amdgcn_s_setprio(1);
            #pragma unroll
            for (int i = 0; i < 2; ++i)
                lsum[i] = mfma16(pf[i], ones, lsum[i]);
            #pragma unroll
            for (int dn = 0; dn < 8; ++dn) {
                bf16x8 vf = *(const bf16x8*)(
                    &Vc[(dn * 16 + l16) * 32 + ((quad ^ (l16 & 3)) << 3)]);
                #pragma unroll
                for (int i = 0; i < 2; ++i)
                    o[i][dn] = mfma16(pf[i], vf, o[i][dn]);
            }
            __builtin_amdgcn_s_setprio(0);
        }
        __syncthreads();   // drains vmcnt(0): next tile's loads have landed
        cur ^= 1;
    }

    // ---- write Ao[b][s][h*128+d] ----
    #pragma unroll
    for (int i = 0; i < 2; ++i) {
        #pragma unroll
        for (int r = 0; r < 4; ++r) {
            float inv = 1.0f / lsum[i][r];
            int row = qr0 + i * 16 + quad * 4 + r;
            size_t base = ((size_t)b * 2048 + row) * 4096 + (size_t)h * 128;
            #pragma unroll
            for (int dn = 0; dn < 8; ++dn)
                Ao[base + dn * 16 + l16] = __float2bfloat16(o[i][dn][r] * inv);
        }
    }
}

// ---------------------------------------------------------------------------
extern "C" void kernel_launch(void* const* d_in, const int* in_sizes, int n_in,
                              void* d_out, int out_size, void* d_ws, size_t ws_size,
                              hipStream_t stream) {
    const int*   positions = (const int*)d_in[0];
    const float* hidden    = (const float*)d_in[1];
    const float* wqkv      = (const float*)d_in[2];
    const float* wo        = (const float*)d_in[3];
    float* out = (float*)d_out;

    __hip_bfloat16* WqkvT = (__hip_bfloat16*)d_ws;        // 25165824
    __hip_bfloat16* WoT   = WqkvT + 25165824;             // 16777216
    __hip_bfloat16* Hb    = WoT   + 16777216;             // 16777216
    __hip_bfloat16* Qr    = Hb    + 16777216;             // 16777216
    __hip_bfloat16* Kr    = Qr    + 16777216;             // 4194304
    __hip_bfloat16* Vv    = Kr    + 4194304;              // 4194304
    __hip_bfloat16* Ao    = WqkvT;                        // alias (dead after GEMM1)
    __hip_bfloat16* Vt    = Hb;                           // alias (dead after GEMM1)
    // total 160 MiB

    convert_kernel<<<16777216 / 1024, 256, 0, stream>>>(hidden, Hb, 16777216);
    transpose_f32_bf16_kernel<<<dim3(6144 / 64, 4096 / 64), 256, 0, stream>>>(
        wqkv, WqkvT, 4096, 6144);
    transpose_f32_bf16_kernel<<<dim3(4096 / 64, 4096 / 64), 256, 0, stream>>>(
        wo, WoT, 4096, 4096);

    gemm_bt_kernel<1><<<dim3(6144 / 256, 4096 / 128), 512, 0, stream>>>(
        Hb, WqkvT, nullptr, Qr, Kr, Vv, 4096, 6144, 4096);

    rope_kernel<<<(131072 * 64) / 256, 256, 0, stream>>>(
        Qr, positions, 131072, 16, 0.08838834764831845f);
    rope_kernel<<<(32768  * 64) / 256, 256, 0, stream>>>(
        Kr, positions, 32768, 14, 1.0f);

    transpose_bf16_kernel<<<dim3(128 / 64, 2048 / 64, 16), 256, 0, stream>>>(
        Vv, Vt, 2048, 128);

    attn_kernel<<<dim3(2048 / 128, 32, 2), 256, 0, stream>>>(Qr, Kr, Vt, Ao);

    gemm_bt_kernel<0><<<dim3(4096 / 256, 4096 / 128), 512, 0, stream>>>(
        Ao, WoT, out, nullptr, nullptr, nullptr, 4096, 4096, 4096);
}